// Round 5
// baseline (110.229 us; speedup 1.0000x reference)
//
#include <hip/hip_runtime.h>
#include <hip/hip_bf16.h>

typedef short s4 __attribute__((ext_vector_type(4)));
typedef short s8 __attribute__((ext_vector_type(8)));
typedef float f4 __attribute__((ext_vector_type(4)));

#define MFMA16(a, b, c) __builtin_amdgcn_mfma_f32_16x16x16bf16_1k(a, b, c, 0, 0, 0)

__device__ __forceinline__ short f2bf(float f) {
    union { float f; unsigned u; } v; v.f = f;
    unsigned r = v.u + 0x7fffu + ((v.u >> 16) & 1u);   // RNE
    return (short)(r >> 16);
}

// ---------------------------------------------------------------------------
// Kernel 0: pack W (f32 [1024][64]) -> fragment-ordered bf16 (proven).
// s8 idx = (ks*64 + ln)*2 + h ; holds B-frags (nf=2h, e0..3),(nf=2h+1, e0..3)
// with elem e = W[16*ks + 4*(ln>>4) + e][16*nf + (ln&15)].
// ---------------------------------------------------------------------------
struct WcArgs { const float* W[3]; unsigned short* Wf; };

__global__ __launch_bounds__(256) void wconv_kernel(WcArgs a) {
    const int which = blockIdx.y;
    const int id = blockIdx.x * 256 + threadIdx.x;      // 0..8191
    const int ks = id >> 7, ln = (id >> 1) & 63, h = id & 1;
    const int lg = ln >> 4, lr = ln & 15;
    const float* W = a.W[which];
    s8 o;
    #pragma unroll
    for (int i = 0; i < 8; ++i) {
        int nf = 2 * h + (i >> 2), e = i & 3;
        o[i] = f2bf(W[(ks * 16 + 4 * lg + e) * 64 + nf * 16 + lr]);
    }
    ((s8*)a.Wf)[(size_t)which * 8192 + id] = o;
}

// ---------------------------------------------------------------------------
// Kernel 1 v5: R4 structure + NON-TEMPORAL X loads (single-variable A/B).
// Theory: ~48% of X reads hit L3 (inputs re-resident across timed replays)
// and the L3-hit path serves only ~2.3 TB/s; nt loads bypass L2/L3 so X
// streams from HBM at the m13 copy rate and stops polluting L3.
// Block = 16 rows x full K. Phase 1: linear nt stage to LDS (bf16).
// Phase 2: wave w owns K-quarter; W frags from packed L2. Phase 3: LDS
// K-reduction. grid (1024, 3), 256 thr, LDS 33 KB (4 blocks/CU).
// ---------------------------------------------------------------------------
struct ProjArgs {
    const float* X[3];
    const float* b[3];
    const unsigned short* Wf;
    unsigned short* O[3];
};

__global__ __launch_bounds__(256) void proj_kernel(ProjArgs args) {
    __shared__ short lX[16 * 1032];   // [row][1032] bf16

    const int t  = threadIdx.x;
    const int wv = t >> 6, ln = t & 63, lg = ln >> 4, lr = ln & 15;
    const int which = blockIdx.y;
    const int r0 = blockIdx.x * 16;
    const float* X = args.X[which];

    // ---- phase 1: linear streaming stage, f32 -> bf16, NT loads ----
    #pragma unroll
    for (int h = 0; h < 2; ++h) {
        f4 xr[8];
        #pragma unroll
        for (int i = 0; i < 8; ++i)
            xr[i] = __builtin_nontemporal_load(
                        (const f4*)(X + (size_t)(r0 + h * 8 + i) * 1024 + 4 * t));
        #pragma unroll
        for (int i = 0; i < 8; ++i) {
            int row = h * 8 + i;
            s4 a;
            a[0] = f2bf(xr[i][0]); a[1] = f2bf(xr[i][1]);
            a[2] = f2bf(xr[i][2]); a[3] = f2bf(xr[i][3]);
            *(s4*)&lX[row * 1032 + 4 * t] = a;
        }
    }
    __syncthreads();

    // ---- phase 2: wave wv owns k in [wv*256, wv*256+256) ----
    f4 acc[4] = {f4{0,0,0,0}, f4{0,0,0,0}, f4{0,0,0,0}, f4{0,0,0,0}};
    const s8* wfp = (const s8*)args.Wf + (size_t)which * 8192 + (wv * 16) * 128 + ln * 2;

    s8 wq[2][4][2];
    #pragma unroll
    for (int ks = 0; ks < 4; ++ks) {
        wq[0][ks][0] = wfp[ks * 128];
        wq[0][ks][1] = wfp[ks * 128 + 1];
    }
    #pragma unroll
    for (int j = 0; j < 4; ++j) {
        if (j < 3) {
            #pragma unroll
            for (int ks = 0; ks < 4; ++ks) {
                wq[(j + 1) & 1][ks][0] = wfp[((j + 1) * 4 + ks) * 128];
                wq[(j + 1) & 1][ks][1] = wfp[((j + 1) * 4 + ks) * 128 + 1];
            }
        }
        #pragma unroll
        for (int ks = 0; ks < 4; ++ks) {
            s4 a = *(const s4*)&lX[lr * 1032 + wv * 256 + j * 64 + ks * 16 + 4 * lg];
            s8 wa = wq[j & 1][ks][0], wb = wq[j & 1][ks][1];
            s4 w0 = __builtin_shufflevector(wa, wa, 0, 1, 2, 3);
            s4 w1 = __builtin_shufflevector(wa, wa, 4, 5, 6, 7);
            s4 w2 = __builtin_shufflevector(wb, wb, 0, 1, 2, 3);
            s4 w3 = __builtin_shufflevector(wb, wb, 4, 5, 6, 7);
            acc[0] = MFMA16(a, w0, acc[0]);
            acc[1] = MFMA16(a, w1, acc[1]);
            acc[2] = MFMA16(a, w2, acc[2]);
            acc[3] = MFMA16(a, w3, acc[3]);
        }
    }
    __syncthreads();

    // ---- phase 3: cross-wave K-reduction (alias LDS) ----
    float* red = (float*)lX;           // [3][16][68] floats
    if (wv > 0) {
        #pragma unroll
        for (int nf = 0; nf < 4; ++nf)
            #pragma unroll
            for (int e = 0; e < 4; ++e)
                red[(wv - 1) * 1088 + (4 * lg + e) * 68 + nf * 16 + lr] = acc[nf][e];
    }
    __syncthreads();
    if (wv == 0) {
        const float* bias = args.b[which];
        unsigned short* O = args.O[which] + (size_t)r0 * 64;
        #pragma unroll
        for (int nf = 0; nf < 4; ++nf) {
            float bs = bias[nf * 16 + lr];
            #pragma unroll
            for (int e = 0; e < 4; ++e) {
                int row = 4 * lg + e, col = nf * 16 + lr;
                float s = acc[nf][e] + red[row * 68 + col] + red[1088 + row * 68 + col]
                        + red[2176 + row * 68 + col] + bs;
                O[(size_t)row * 64 + col] = (unsigned short)f2bf(s);
            }
        }
    }
}

// ---------------------------------------------------------------------------
// Kernel 2: causal flash attention (unchanged, correct, ~7 us).
// ---------------------------------------------------------------------------
__global__ __launch_bounds__(256) void attn_kernel(const unsigned short* __restrict__ qp,
                                                   const unsigned short* __restrict__ kp,
                                                   const unsigned short* __restrict__ vp,
                                                   float* __restrict__ out) {
    __shared__ short lK[64][72];   // [key][d]
    __shared__ short lV[64][76];   // [d][key] (transposed)

    const int t  = threadIdx.x;
    const int wv = t >> 6, ln = t & 63, lg = ln >> 4, lr = ln & 15;
    const int b  = blockIdx.y, qt = blockIdx.x;
    const int q0 = qt * 64;
    const int qrow = q0 + wv * 16 + lr;

    const unsigned short* qpb = qp + (size_t)b * 2048 * 64;

    s4 qf[4];
    #pragma unroll
    for (int ks = 0; ks < 4; ++ks)
        qf[ks] = *(const s4*)(qpb + (size_t)qrow * 64 + ks * 16 + 4 * lg);

    f4 accO[4] = {f4{0,0,0,0}, f4{0,0,0,0}, f4{0,0,0,0}, f4{0,0,0,0}};
    float m = -3e38f, lsum = 0.f;

    for (int kt = 0; kt <= qt; ++kt) {
        const unsigned short* kpb = kp + ((size_t)b * 2048 + kt * 64) * 64;
        const unsigned short* vpb = vp + ((size_t)b * 2048 + kt * 64) * 64;

        #pragma unroll
        for (int i = 0; i < 2; ++i) {
            int f = t + i * 256;
            int r = f >> 3, c8 = f & 7;
            s8 k8 = *(const s8*)(kpb + (size_t)r * 64 + c8 * 8);
            *(s8*)&lK[r][c8 * 8] = k8;
            s8 v8 = *(const s8*)(vpb + (size_t)r * 64 + c8 * 8);
            #pragma unroll
            for (int j = 0; j < 8; ++j) lV[c8 * 8 + j][r] = v8[j];
        }
        __syncthreads();

        f4 st[4];
        #pragma unroll
        for (int kf = 0; kf < 4; ++kf) {
            f4 a = f4{0,0,0,0};
            #pragma unroll
            for (int ks = 0; ks < 4; ++ks) {
                s4 kfr = *(const s4*)&lK[kf * 16 + lr][ks * 16 + 4 * lg];
                a = MFMA16(kfr, qf[ks], a);
            }
            st[kf] = a;
        }

        const bool diag = (kt == qt);
        const int kbase = kt * 64;
        float smax = -3e38f;
        #pragma unroll
        for (int kf = 0; kf < 4; ++kf) {
            #pragma unroll
            for (int e = 0; e < 4; ++e) {
                float s = st[kf][e] * 0.125f;
                if (diag && (kbase + kf * 16 + 4 * lg + e > qrow)) s = -3e38f;
                st[kf][e] = s;
                smax = fmaxf(smax, s);
            }
        }
        smax = fmaxf(smax, __shfl_xor(smax, 16));
        smax = fmaxf(smax, __shfl_xor(smax, 32));

        float mnew  = fmaxf(m, smax);
        float scale = __expf(m - mnew);
        float psum  = 0.f;
        s4 pf[4];
        #pragma unroll
        for (int kf = 0; kf < 4; ++kf) {
            f4 p;
            #pragma unroll
            for (int e = 0; e < 4; ++e) { p[e] = __expf(st[kf][e] - mnew); psum += p[e]; }
            s4 pb; pb[0]=f2bf(p[0]); pb[1]=f2bf(p[1]); pb[2]=f2bf(p[2]); pb[3]=f2bf(p[3]);
            pf[kf] = pb;
        }
        psum += __shfl_xor(psum, 16);
        psum += __shfl_xor(psum, 32);
        lsum = lsum * scale + psum;
        m = mnew;
        #pragma unroll
        for (int df = 0; df < 4; ++df) accO[df] *= scale;

        #pragma unroll
        for (int df = 0; df < 4; ++df) {
            #pragma unroll
            for (int kf = 0; kf < 4; ++kf) {
                s4 vf = *(const s4*)&lV[df * 16 + lr][kf * 16 + 4 * lg];
                accO[df] = MFMA16(vf, pf[kf], accO[df]);
            }
        }
        __syncthreads();
    }

    float inv = 1.f / lsum;
    float* ob = out + ((size_t)b * 2048 + qrow) * 64;
    #pragma unroll
    for (int df = 0; df < 4; ++df) {
        f4 o;
        #pragma unroll
        for (int e = 0; e < 4; ++e) o[e] = accO[df][e] * inv;
        *(f4*)(ob + df * 16 + 4 * lg) = o;
    }
}

// ---------------------------------------------------------------------------
extern "C" void kernel_launch(void* const* d_in, const int* in_sizes, int n_in,
                              void* d_out, int out_size, void* d_ws, size_t ws_size,
                              hipStream_t stream) {
    const float* q  = (const float*)d_in[0];
    const float* k  = (const float*)d_in[1];
    const float* v  = (const float*)d_in[2];
    // d_in[3] = causal mask (deterministic tril) — computed analytically
    const float* Wq = (const float*)d_in[4];
    const float* bq = (const float*)d_in[5];
    const float* Wk = (const float*)d_in[6];
    const float* bk = (const float*)d_in[7];
    const float* Wv = (const float*)d_in[8];
    const float* bv = (const float*)d_in[9];

    unsigned short* qp = (unsigned short*)d_ws;            // [16384][64] bf16
    unsigned short* kp = qp + (size_t)16384 * 64;
    unsigned short* vp = kp + (size_t)16384 * 64;
    unsigned short* Wf = vp + (size_t)16384 * 64;          // 3 x 128 KB packed W frags

    WcArgs wa;
    wa.W[0] = Wq; wa.W[1] = Wk; wa.W[2] = Wv;
    wa.Wf = Wf;
    wconv_kernel<<<dim3(32, 3), 256, 0, stream>>>(wa);

    ProjArgs pa;
    pa.X[0] = q;  pa.X[1] = k;  pa.X[2] = v;
    pa.b[0] = bq; pa.b[1] = bk; pa.b[2] = bv;
    pa.Wf = Wf;
    pa.O[0] = qp; pa.O[1] = kp; pa.O[2] = vp;
    proj_kernel<<<dim3(1024, 3), 256, 0, stream>>>(pa);

    attn_kernel<<<dim3(32, 8), 256, 0, stream>>>(qp, kp, vp, (float*)d_out);
}

// Round 6
// 90.939 us; speedup vs baseline: 1.2121x; 1.2121x over previous
//
#include <hip/hip_runtime.h>
#include <hip/hip_bf16.h>

typedef short s4 __attribute__((ext_vector_type(4)));
typedef short s8 __attribute__((ext_vector_type(8)));
typedef float f4 __attribute__((ext_vector_type(4)));

#define MFMA16(a, b, c) __builtin_amdgcn_mfma_f32_16x16x16bf16_1k(a, b, c, 0, 0, 0)

__device__ __forceinline__ short f2bf(float f) {
    union { float f; unsigned u; } v; v.f = f;
    unsigned r = v.u + 0x7fffu + ((v.u >> 16) & 1u);   // RNE
    return (short)(r >> 16);
}

// ---------------------------------------------------------------------------
// Kernel 0: pack W (f32 [1024][64]) -> fragment-ordered bf16 (proven).
// ---------------------------------------------------------------------------
struct WcArgs { const float* W[3]; unsigned short* Wf; };

__global__ __launch_bounds__(256) void wconv_kernel(WcArgs a) {
    const int which = blockIdx.y;
    const int id = blockIdx.x * 256 + threadIdx.x;      // 0..8191
    const int ks = id >> 7, ln = (id >> 1) & 63, h = id & 1;
    const int lg = ln >> 4, lr = ln & 15;
    const float* W = a.W[which];
    s8 o;
    #pragma unroll
    for (int i = 0; i < 8; ++i) {
        int nf = 2 * h + (i >> 2), e = i & 3;
        o[i] = f2bf(W[(ks * 16 + 4 * lg + e) * 64 + nf * 16 + lr]);
    }
    ((s8*)a.Wf)[(size_t)which * 8192 + id] = o;
}

// ---------------------------------------------------------------------------
// Kernel 1: projections (frozen from round 5: nt X loads, 54 us cold).
// ---------------------------------------------------------------------------
struct ProjArgs {
    const float* X[3];
    const float* b[3];
    const unsigned short* Wf;
    unsigned short* O[3];
};

__global__ __launch_bounds__(256) void proj_kernel(ProjArgs args) {
    __shared__ short lX[16 * 1032];

    const int t  = threadIdx.x;
    const int wv = t >> 6, ln = t & 63, lg = ln >> 4, lr = ln & 15;
    const int which = blockIdx.y;
    const int r0 = blockIdx.x * 16;
    const float* X = args.X[which];

    #pragma unroll
    for (int h = 0; h < 2; ++h) {
        f4 xr[8];
        #pragma unroll
        for (int i = 0; i < 8; ++i)
            xr[i] = __builtin_nontemporal_load(
                        (const f4*)(X + (size_t)(r0 + h * 8 + i) * 1024 + 4 * t));
        #pragma unroll
        for (int i = 0; i < 8; ++i) {
            int row = h * 8 + i;
            s4 a;
            a[0] = f2bf(xr[i][0]); a[1] = f2bf(xr[i][1]);
            a[2] = f2bf(xr[i][2]); a[3] = f2bf(xr[i][3]);
            *(s4*)&lX[row * 1032 + 4 * t] = a;
        }
    }
    __syncthreads();

    f4 acc[4] = {f4{0,0,0,0}, f4{0,0,0,0}, f4{0,0,0,0}, f4{0,0,0,0}};
    const s8* wfp = (const s8*)args.Wf + (size_t)which * 8192 + (wv * 16) * 128 + ln * 2;

    s8 wq[2][4][2];
    #pragma unroll
    for (int ks = 0; ks < 4; ++ks) {
        wq[0][ks][0] = wfp[ks * 128];
        wq[0][ks][1] = wfp[ks * 128 + 1];
    }
    #pragma unroll
    for (int j = 0; j < 4; ++j) {
        if (j < 3) {
            #pragma unroll
            for (int ks = 0; ks < 4; ++ks) {
                wq[(j + 1) & 1][ks][0] = wfp[((j + 1) * 4 + ks) * 128];
                wq[(j + 1) & 1][ks][1] = wfp[((j + 1) * 4 + ks) * 128 + 1];
            }
        }
        #pragma unroll
        for (int ks = 0; ks < 4; ++ks) {
            s4 a = *(const s4*)&lX[lr * 1032 + wv * 256 + j * 64 + ks * 16 + 4 * lg];
            s8 wa = wq[j & 1][ks][0], wb = wq[j & 1][ks][1];
            s4 w0 = __builtin_shufflevector(wa, wa, 0, 1, 2, 3);
            s4 w1 = __builtin_shufflevector(wa, wa, 4, 5, 6, 7);
            s4 w2 = __builtin_shufflevector(wb, wb, 0, 1, 2, 3);
            s4 w3 = __builtin_shufflevector(wb, wb, 4, 5, 6, 7);
            acc[0] = MFMA16(a, w0, acc[0]);
            acc[1] = MFMA16(a, w1, acc[1]);
            acc[2] = MFMA16(a, w2, acc[2]);
            acc[3] = MFMA16(a, w3, acc[3]);
        }
    }
    __syncthreads();

    float* red = (float*)lX;
    if (wv > 0) {
        #pragma unroll
        for (int nf = 0; nf < 4; ++nf)
            #pragma unroll
            for (int e = 0; e < 4; ++e)
                red[(wv - 1) * 1088 + (4 * lg + e) * 68 + nf * 16 + lr] = acc[nf][e];
    }
    __syncthreads();
    if (wv == 0) {
        const float* bias = args.b[which];
        unsigned short* O = args.O[which] + (size_t)r0 * 64;
        #pragma unroll
        for (int nf = 0; nf < 4; ++nf) {
            float bs = bias[nf * 16 + lr];
            #pragma unroll
            for (int e = 0; e < 4; ++e) {
                int row = 4 * lg + e, col = nf * 16 + lr;
                float s = acc[nf][e] + red[row * 68 + col] + red[1088 + row * 68 + col]
                        + red[2176 + row * 68 + col] + bs;
                O[(size_t)row * 64 + col] = (unsigned short)f2bf(s);
            }
        }
    }
}

// ---------------------------------------------------------------------------
// Kernel 2 v6: causal flash attention, intra-block 2-way KV-split.
// 512 thr (8 waves): waves 0-3 = kv-half A (tiles 0..h-1), waves 4-7 = half B
// (tiles h..qt), h = ceil((qt+1)/2). Private online-softmax per half; LDS
// merge at end. Register prefetch (4 s8/thread) + double-buffered LDS,
// ONE barrier per iteration. Odd-dword LDS strides (74/78) -> <=2-way.
// grid (32, 8). Critical path: 16 iters (was 32).
// ---------------------------------------------------------------------------
__global__ __launch_bounds__(512) void attn_kernel(const unsigned short* __restrict__ qp,
                                                   const unsigned short* __restrict__ kp,
                                                   const unsigned short* __restrict__ vp,
                                                   float* __restrict__ out) {
    __shared__ short lK[2][2][64][74];   // [half][buf][key][d]
    __shared__ short lV[2][2][64][78];   // [half][buf][d][key]

    const int t    = threadIdx.x;
    const int wave = t >> 6, ln = t & 63, lg = ln >> 4, lr = ln & 15;
    const int half = wave >> 2, hw = wave & 3;
    const int b = blockIdx.y, qt = blockIdx.x;
    const int qrow = qt * 64 + hw * 16 + lr;
    const int h = (qt + 2) >> 1;

    // staging role: 128-thread groups g: 0=K half0, 1=V half0, 2=K half1, 3=V half1
    const int g = t >> 7, gi = t & 127, ghalf = g >> 1;
    const bool isV = (g & 1) != 0;
    const unsigned short* tb = (isV ? vp : kp) + (size_t)b * 2048 * 64;

    const unsigned short* qpb = qp + (size_t)b * 2048 * 64;
    s4 qf[4];
    #pragma unroll
    for (int ks = 0; ks < 4; ++ks)
        qf[ks] = *(const s4*)(qpb + (size_t)qrow * 64 + ks * 16 + 4 * lg);

    f4 accO[4] = {f4{0,0,0,0}, f4{0,0,0,0}, f4{0,0,0,0}, f4{0,0,0,0}};
    float m = -3e38f, lsum = 0.f;

    // prologue: prefetch iter-0 tile for this thread's (tensor, half)
    s8 stg[4];
    {
        const unsigned short* p = tb + (size_t)(ghalf ? h : 0) * 4096;
        #pragma unroll
        for (int i = 0; i < 4; ++i)
            stg[i] = *(const s8*)(p + (gi + 128 * i) * 8);
    }

    int buf = 0;
    for (int j = 0; j < h; ++j) {
        // write staged regs -> LDS[ghalf][buf]
        if (!isV) {
            #pragma unroll
            for (int i = 0; i < 4; ++i) {
                int s = gi + 128 * i, r = s >> 3, c8 = s & 7;
                *(s8*)&lK[ghalf][buf][r][c8 * 8] = stg[i];
            }
        } else {
            #pragma unroll
            for (int i = 0; i < 4; ++i) {
                int s = gi + 128 * i, r = s >> 3, c8 = s & 7;
                #pragma unroll
                for (int jj = 0; jj < 8; ++jj)
                    lV[ghalf][buf][c8 * 8 + jj][r] = stg[i][jj];
            }
        }
        __syncthreads();

        // prefetch next tile (hides under compute below)
        if (j + 1 < h) {
            const unsigned short* p = tb + (size_t)((ghalf ? h : 0) + j + 1) * 4096;
            #pragma unroll
            for (int i = 0; i < 4; ++i)
                stg[i] = *(const s8*)(p + (gi + 128 * i) * 8);
        }

        const int kt = (half ? h : 0) + j;
        if (kt <= qt) {                      // half-B pad iter (qt even) skips
            // S^T = K . Q^T
            f4 st[4];
            #pragma unroll
            for (int kf = 0; kf < 4; ++kf) {
                f4 a = f4{0,0,0,0};
                #pragma unroll
                for (int ks = 0; ks < 4; ++ks) {
                    s4 kfr = *(const s4*)&lK[half][buf][kf * 16 + lr][ks * 16 + 4 * lg];
                    a = MFMA16(kfr, qf[ks], a);
                }
                st[kf] = a;
            }

            const bool diag = (kt == qt);
            const int kbase = kt * 64;
            float smax = -3e38f;
            #pragma unroll
            for (int kf = 0; kf < 4; ++kf) {
                #pragma unroll
                for (int e = 0; e < 4; ++e) {
                    float s = st[kf][e] * 0.125f;
                    if (diag && (kbase + kf * 16 + 4 * lg + e > qrow)) s = -3e38f;
                    st[kf][e] = s;
                    smax = fmaxf(smax, s);
                }
            }
            smax = fmaxf(smax, __shfl_xor(smax, 16));
            smax = fmaxf(smax, __shfl_xor(smax, 32));

            float mnew  = fmaxf(m, smax);
            float scale = __expf(m - mnew);
            float psum  = 0.f;
            s4 pf[4];
            #pragma unroll
            for (int kf = 0; kf < 4; ++kf) {
                f4 p;
                #pragma unroll
                for (int e = 0; e < 4; ++e) { p[e] = __expf(st[kf][e] - mnew); psum += p[e]; }
                s4 pb; pb[0]=f2bf(p[0]); pb[1]=f2bf(p[1]); pb[2]=f2bf(p[2]); pb[3]=f2bf(p[3]);
                pf[kf] = pb;
            }
            psum += __shfl_xor(psum, 16);
            psum += __shfl_xor(psum, 32);
            lsum = lsum * scale + psum;
            m = mnew;
            #pragma unroll
            for (int df = 0; df < 4; ++df) accO[df] *= scale;

            #pragma unroll
            for (int df = 0; df < 4; ++df) {
                #pragma unroll
                for (int kf = 0; kf < 4; ++kf) {
                    s4 vf = *(const s4*)&lV[half][buf][df * 16 + lr][kf * 16 + 4 * lg];
                    accO[df] = MFMA16(vf, pf[kf], accO[df]);
                }
            }
        }
        buf ^= 1;
    }

    // ---- merge halves: B publishes (m, l, accO) via LDS; A combines ----
    __syncthreads();
    float* ex = (float*)&lK[0][0][0][0];     // 4*64*19 floats = 19456 B < 37888 B
    const int idx = (hw * 64 + ln) * 19;
    if (half == 1) {
        ex[idx + 0] = m;
        ex[idx + 1] = lsum;
        #pragma unroll
        for (int df = 0; df < 4; ++df)
            #pragma unroll
            for (int e = 0; e < 4; ++e)
                ex[idx + 2 + df * 4 + e] = accO[df][e];
    }
    __syncthreads();
    if (half == 0) {
        float mB = ex[idx + 0], lB = ex[idx + 1];
        float mx = fmaxf(m, mB);
        float sA = __expf(m - mx), sB = __expf(mB - mx);
        float linv = 1.f / (lsum * sA + lB * sB);
        float* ob = out + ((size_t)b * 2048 + qrow) * 64;
        #pragma unroll
        for (int df = 0; df < 4; ++df) {
            f4 o;
            #pragma unroll
            for (int e = 0; e < 4; ++e)
                o[e] = (accO[df][e] * sA + ex[idx + 2 + df * 4 + e] * sB) * linv;
            *(f4*)(ob + df * 16 + 4 * lg) = o;
        }
    }
}

// ---------------------------------------------------------------------------
extern "C" void kernel_launch(void* const* d_in, const int* in_sizes, int n_in,
                              void* d_out, int out_size, void* d_ws, size_t ws_size,
                              hipStream_t stream) {
    const float* q  = (const float*)d_in[0];
    const float* k  = (const float*)d_in[1];
    const float* v  = (const float*)d_in[2];
    // d_in[3] = causal mask (deterministic tril) — computed analytically
    const float* Wq = (const float*)d_in[4];
    const float* bq = (const float*)d_in[5];
    const float* Wk = (const float*)d_in[6];
    const float* bk = (const float*)d_in[7];
    const float* Wv = (const float*)d_in[8];
    const float* bv = (const float*)d_in[9];

    unsigned short* qp = (unsigned short*)d_ws;            // [16384][64] bf16
    unsigned short* kp = qp + (size_t)16384 * 64;
    unsigned short* vp = kp + (size_t)16384 * 64;
    unsigned short* Wf = vp + (size_t)16384 * 64;          // 3 x 128 KB packed W frags

    WcArgs wa;
    wa.W[0] = Wq; wa.W[1] = Wk; wa.W[2] = Wv;
    wa.Wf = Wf;
    wconv_kernel<<<dim3(32, 3), 256, 0, stream>>>(wa);

    ProjArgs pa;
    pa.X[0] = q;  pa.X[1] = k;  pa.X[2] = v;
    pa.b[0] = bq; pa.b[1] = bk; pa.b[2] = bv;
    pa.Wf = Wf;
    pa.O[0] = qp; pa.O[1] = kp; pa.O[2] = vp;
    proj_kernel<<<dim3(1024, 3), 256, 0, stream>>>(pa);

    attn_kernel<<<dim3(32, 8), 512, 0, stream>>>(qp, kp, vp, (float*)d_out);
}